// Round 9
// baseline (376.074 us; speedup 1.0000x reference)
//
#include <hip/hip_runtime.h>
#include <math.h>

#define NB    32768
#define DDIM  64
#define HDIM  512
#define PDIM  23        // 3*K - 1
#define KBINS 8
#define BM    16
#define NCOLS (DDIM * PDIM)   // 1472
#define CHUNK 368             // 23 n-tiles of 16 = 16 d's worth of params
#define PSTRIDE 372           // f32 per pstage row (368 + pad)

#define RQ_BOUND  4.0f
#define RQ_MINBIN 0.001f
#define RQ_MINDER 0.001f

typedef __attribute__((ext_vector_type(8))) _Float16 half8;
typedef __attribute__((ext_vector_type(4))) float f32x4;
typedef unsigned short ushort_t;

// ---------------------------------------------------------------------------
// prep: bake masks, convert to fp16.  M1[h,i] = i <= h%63 ; M2[o,h] = o/23 > h%63
// ---------------------------------------------------------------------------
__global__ __launch_bounds__(256) void prep_f16(const float* __restrict__ W1,
                                                const float* __restrict__ W2,
                                                _Float16* __restrict__ W1f,
                                                _Float16* __restrict__ W2f) {
    int idx = blockIdx.x * 256 + threadIdx.x;
    const int n1 = HDIM * DDIM;          // 32768
    if (idx < n1) {
        int h = idx >> 6, i = idx & 63;
        W1f[idx] = (_Float16)((i <= (h % 63)) ? W1[idx] : 0.0f);
    } else {
        int j = idx - n1;
        if (j < NCOLS * HDIM) {
            int o = j >> 9, hh = j & 511;
            W2f[j] = (_Float16)(((o / PDIM) > (hh % 63)) ? W2[j] : 0.0f);
        }
    }
}

// ---------------------------------------------------------------------------
// fast transcendentals (validated round 5)
// ---------------------------------------------------------------------------
__device__ __forceinline__ float fexp(float v)  { return __expf(v); }
__device__ __forceinline__ float flog(float v)  { return __logf(v); }
__device__ __forceinline__ float fdiv(float a, float b) { return __fdividef(a, b); }

// ---------------------------------------------------------------------------
// rational-quadratic spline (validated rounds 1-8)
// ---------------------------------------------------------------------------
__device__ __forceinline__ void rqs_eval(const float* prm, float xorig,
                                         float& yo, float& ldo) {
    const float xc = fminf(fmaxf(xorig, -RQ_BOUND), RQ_BOUND);
    const bool inside = (xorig >= -RQ_BOUND) && (xorig <= RQ_BOUND);

    float xk[KBINS + 1], yk[KBINS + 1], dd[KBINS + 1];
    {
        float m = prm[0];
        #pragma unroll
        for (int i = 1; i < KBINS; ++i) m = fmaxf(m, prm[i]);
        float e[KBINS]; float s = 0.0f;
        #pragma unroll
        for (int i = 0; i < KBINS; ++i) { e[i] = fexp(prm[i] - m); s += e[i]; }
        const float inv = fdiv(1.0f, s);
        float c = 0.0f;
        xk[0] = -RQ_BOUND;
        #pragma unroll
        for (int i = 0; i < KBINS; ++i) {
            float w = RQ_MINBIN + (1.0f - RQ_MINBIN * KBINS) * (e[i] * inv);
            c += w;
            xk[i + 1] = -RQ_BOUND + 2.0f * RQ_BOUND * c;
        }
        xk[KBINS] = RQ_BOUND;
    }
    {
        float m = prm[8];
        #pragma unroll
        for (int i = 1; i < KBINS; ++i) m = fmaxf(m, prm[8 + i]);
        float e[KBINS]; float s = 0.0f;
        #pragma unroll
        for (int i = 0; i < KBINS; ++i) { e[i] = fexp(prm[8 + i] - m); s += e[i]; }
        const float inv = fdiv(1.0f, s);
        float c = 0.0f;
        yk[0] = -RQ_BOUND;
        #pragma unroll
        for (int i = 0; i < KBINS; ++i) {
            float h = RQ_MINBIN + (1.0f - RQ_MINBIN * KBINS) * (e[i] * inv);
            c += h;
            yk[i + 1] = -RQ_BOUND + 2.0f * RQ_BOUND * c;
        }
        yk[KBINS] = RQ_BOUND;
    }
    dd[0] = 1.0f;
    #pragma unroll
    for (int i = 0; i < KBINS - 1; ++i) {
        const float v = prm[16 + i];
        const float e = fexp(-fabsf(v));
        dd[i + 1] = RQ_MINDER + flog(1.0f + e) + fmaxf(v, 0.0f);
    }
    dd[KBINS] = 1.0f;

    int idx = 0;
    #pragma unroll
    for (int i = 1; i < KBINS; ++i) idx += (xc >= xk[i]) ? 1 : 0;

    float x_k = xk[0], x_k1 = xk[1];
    float y_k = yk[0], y_k1 = yk[1];
    float d_k = dd[0], d_k1 = dd[1];
    #pragma unroll
    for (int i = 1; i < KBINS; ++i) {
        const bool mm = (idx == i);
        x_k  = mm ? xk[i]     : x_k;
        x_k1 = mm ? xk[i + 1] : x_k1;
        y_k  = mm ? yk[i]     : y_k;
        y_k1 = mm ? yk[i + 1] : y_k1;
        d_k  = mm ? dd[i]     : d_k;
        d_k1 = mm ? dd[i + 1] : d_k1;
    }

    const float w_k = x_k1 - x_k;
    const float h_k = y_k1 - y_k;
    const float rw  = fdiv(1.0f, w_k);
    const float s   = h_k * rw;
    const float th  = (xc - x_k) * rw;
    const float omt = 1.0f - th;
    const float t1m = th * omt;
    const float num = h_k * (s * th * th + d_k * t1m);
    const float den = s + (d_k1 + d_k - 2.0f * s) * t1m;
    const float yin = y_k + fdiv(num, den);
    const float dnum = s * s * (d_k1 * th * th + 2.0f * s * t1m + d_k * omt * omt);
    const float ldin = flog(dnum) - 2.0f * flog(den);

    yo  = inside ? yin : xorig;
    ldo = inside ? ldin : 0.0f;
}

// ---------------------------------------------------------------------------
// fused fp16 MFMA kernel — R5 structure at BM=16 for 4 blocks/CU occupancy.
// LDS = 16KB hm + 23.25KB pstage = 40.2KB -> 4 blocks/CU (32 waves, 8/SIMD).
// __launch_bounds__(512, 8) pins VGPR <= 64. Simple kt-loop (R8 proved the
// software pipeline is latency-neutral; occupancy is the lever). 8 waves own
// 3 n-tiles each (wave 7: 2 + dup); single 16-row m-tile. Spline runs on
// threads t<256 (16 rows x 16 d) while waves 4-7 drift into the next kt-loop.
// ---------------------------------------------------------------------------
__global__ __launch_bounds__(512, 8) void fused_flow(
    const float* __restrict__ x,  const float* __restrict__ b1,
    const float* __restrict__ b2, const _Float16* __restrict__ W1f,
    const _Float16* __restrict__ W2f,
    float* __restrict__ z_out, float* __restrict__ ld_out)
{
    __shared__ __align__(16) ushort_t hm[BM * 512];      // 16 KB fp16, swizzled
    __shared__ __align__(16) float pstage[BM * PSTRIDE]; // 23.25 KB

    const int t    = threadIdx.x;
    const int row0 = blockIdx.x * BM;
    const int wv   = t >> 6;
    const int lane = t & 63;
    const int l15  = lane & 15;
    const int lg   = lane >> 4;

    char* hmB = (char*)hm;

    // ---- phase 1: GEMM1 (x from global, W1f from global) -> hm fp16 ----
    {
        f32x4 acc1[4];
        #pragma unroll
        for (int j = 0; j < 4; ++j) acc1[j] = (f32x4){0.f, 0.f, 0.f, 0.f};

        #pragma unroll
        for (int kt = 0; kt < 2; ++kt) {
            half8 a;
            {
                const float* xr = x + (size_t)(row0 + l15) * DDIM + kt * 32 + lg * 8;
                const float4 xa = *(const float4*)(xr);
                const float4 xb = *(const float4*)(xr + 4);
                a[0] = (_Float16)xa.x; a[1] = (_Float16)xa.y;
                a[2] = (_Float16)xa.z; a[3] = (_Float16)xa.w;
                a[4] = (_Float16)xb.x; a[5] = (_Float16)xb.y;
                a[6] = (_Float16)xb.z; a[7] = (_Float16)xb.w;
            }
            #pragma unroll
            for (int j = 0; j < 4; ++j) {
                const int h = (wv * 4 + j) * 16 + l15;
                const half8 b = *(const half8*)(W1f + h * 64 + kt * 32 + lg * 8);
                acc1[j] = __builtin_amdgcn_mfma_f32_16x16x32_f16(a, b, acc1[j], 0, 0, 0);
            }
        }
        #pragma unroll
        for (int j = 0; j < 4; ++j) {
            const int h = (wv * 4 + j) * 16 + l15;
            const float bias = b1[h];
            #pragma unroll
            for (int q = 0; q < 4; ++q) {
                const int r = lg * 4 + q;                 // 0..15
                const _Float16 hv = (_Float16)fmaxf(acc1[j][q] + bias, 0.0f);
                *(ushort_t*)(hmB + r * 1024 + ((h * 2) ^ ((r & 7) << 4))) =
                    __builtin_bit_cast(ushort_t, hv);
            }
        }
    }
    __syncthreads();

    // ---- phase 2: GEMM2 + spline, 4 chunks ----
    float ldacc = 0.0f;
    const int srow = (t >> 4) & 15;  // spline row (t<256 only)
    const int sd   = t & 15;         // spline d-within-chunk
    const int tbase = wv * 3;

    // per-wave W2 base pointers (wave 7's 3rd slot duplicates tile 22)
    const _Float16* w2base[3];
    #pragma unroll
    for (int i = 0; i < 3; ++i) {
        const int tile = (tbase + i < 23) ? (tbase + i) : 22;
        w2base[i] = W2f + (size_t)(tile * 16 + l15) * HDIM + lg * 8;
    }

    for (int c = 0; c < 4; ++c) {
        f32x4 acc[3];
        #pragma unroll
        for (int i = 0; i < 3; ++i) acc[i] = (f32x4){0.f, 0.f, 0.f, 0.f};

        const size_t coff = (size_t)c * (CHUNK * HDIM);

        #pragma unroll 4
        for (int kt = 0; kt < 16; ++kt) {
            const int kb = (kt * 32 + lg * 8) * 2;
            const half8 ah = *(const half8*)(hmB + l15 * 1024 + (kb ^ ((l15 & 7) << 4)));
            half8 bfr[3];
            #pragma unroll
            for (int i = 0; i < 3; ++i)
                bfr[i] = *(const half8*)(w2base[i] + coff + kt * 32);
            #pragma unroll
            for (int i = 0; i < 3; ++i)
                acc[i] = __builtin_amdgcn_mfma_f32_16x16x32_f16(ah, bfr[i], acc[i], 0, 0, 0);
        }

        __syncthreads();   // spline(c-1) readers done with pstage

        // stage full chunk (f32)
        #pragma unroll
        for (int i = 0; i < 3; ++i) {
            if (tbase + i < 23) {
                const int lcol = (tbase + i) * 16 + l15;
                #pragma unroll
                for (int q = 0; q < 4; ++q)
                    pstage[(lg * 4 + q) * PSTRIDE + lcol] = acc[i][q];
            }
        }
        __syncthreads();

        // spline: threads 0..255 -> 16 rows x 16 d's; waves 4-7 drift ahead
        if (t < 256) {
            const int d = c * 16 + sd;
            float prm[PDIM];
            #pragma unroll
            for (int p = 0; p < PDIM; ++p)
                prm[p] = pstage[srow * PSTRIDE + sd * PDIM + p] + b2[d * PDIM + p];
            const float xv = x[(size_t)(row0 + srow) * DDIM + d];
            float yv, lv;
            rqs_eval(prm, xv, yv, lv);
            z_out[(size_t)(row0 + srow) * DDIM + d] = yv;
            ldacc += lv;
        }
        // no barrier here: next kt-loop doesn't touch pstage; stage(c+1) is
        // protected by the barrier after the next kt-loop.
    }

    // ---- logdet: each row's 16 threads are consecutive lanes of one wave ----
    ldacc += __shfl_xor(ldacc, 1, 64);
    ldacc += __shfl_xor(ldacc, 2, 64);
    ldacc += __shfl_xor(ldacc, 4, 64);
    ldacc += __shfl_xor(ldacc, 8, 64);
    if (t < 256 && sd == 0) ld_out[row0 + srow] = ldacc;
}

// ---------------------------------------------------------------------------
extern "C" void kernel_launch(void* const* d_in, const int* in_sizes, int n_in,
                              void* d_out, int out_size, void* d_ws, size_t ws_size,
                              hipStream_t stream) {
    (void)in_sizes; (void)n_in; (void)out_size; (void)ws_size;
    const float* x  = (const float*)d_in[0];
    const float* W1 = (const float*)d_in[1];
    const float* b1 = (const float*)d_in[2];
    const float* W2 = (const float*)d_in[3];
    const float* b2 = (const float*)d_in[4];

    _Float16* W1f = (_Float16*)d_ws;                 // 32768 fp16
    _Float16* W2f = W1f + HDIM * DDIM;               // 753664 fp16 (total ~1.57 MB)
    float* z  = (float*)d_out;
    float* ld = z + (size_t)NB * DDIM;

    const int n_prep = HDIM * DDIM + NCOLS * HDIM;   // 786432
    prep_f16<<<(n_prep + 255) / 256, 256, 0, stream>>>(W1, W2, W1f, W2f);
    fused_flow<<<NB / BM, 512, 0, stream>>>(x, b1, b2, W1f, W2f, z, ld);
}

// Round 10
// 93.572 us; speedup vs baseline: 4.0191x; 4.0191x over previous
//
#include <hip/hip_runtime.h>
#include <math.h>

#define NB    32768
#define DDIM  64
#define HDIM  512
#define PDIM  23        // 3*K - 1
#define KBINS 8
#define BM    32
#define NCOLS (DDIM * PDIM)   // 1472
#define CHUNK 368             // 23 n-tiles of 16 = 16 d's worth of params
#define PSTRIDE 372           // f32 per pstage row (368 + pad)
#define NTILES 92             // NCOLS / 16

#define RQ_BOUND  4.0f
#define RQ_MINBIN 0.001f
#define RQ_MINDER 0.001f

typedef __attribute__((ext_vector_type(8))) _Float16 half8;
typedef __attribute__((ext_vector_type(4))) float f32x4;
typedef unsigned short ushort_t;

// ---------------------------------------------------------------------------
// prep: bake masks, convert to fp16, and store in MFMA-FRAGMENT-MAJOR order so
// every B-frag load in the main kernel is one 1KB fully-coalesced wave read.
//   W1g frag idx = (htile*2 + kt)*64 + lane ; elem j of lane: W1[htile*16+(lane&15)][kt*32+(lane>>4)*8+j]
//   W2g frag idx = (T*16  + kt)*64 + lane  ; elem j of lane: W2[T*16+(lane&15)][kt*32+(lane>>4)*8+j]
// masks: M1[h,i] = i <= h%63 ; M2[o,h] = o/23 > h%63
// ---------------------------------------------------------------------------
__global__ __launch_bounds__(256) void prep_frag(const float* __restrict__ W1,
                                                 const float* __restrict__ W2,
                                                 _Float16* __restrict__ W1g,
                                                 _Float16* __restrict__ W2g) {
    const int gid = blockIdx.x * 256 + threadIdx.x;
    const int NW1 = 32 * 2 * 64;            // 4096 fragment-groups for W1
    if (gid < NW1) {
        const int lane = gid & 63;
        const int tk   = gid >> 6;          // htile*2 + kt
        const int kt   = tk & 1, ht = tk >> 1;
        const int h = ht * 16 + (lane & 15);
        const int k = kt * 32 + (lane >> 4) * 8;
        const float* src = W1 + h * DDIM + k;
        const int hm63 = h % 63;
        half8 v;
        #pragma unroll
        for (int e = 0; e < 8; ++e)
            v[e] = (_Float16)(((k + e) <= hm63) ? src[e] : 0.0f);
        *(half8*)(W1g + (size_t)gid * 8) = v;
    } else {
        const int g2 = gid - NW1;
        if (g2 < NTILES * 16 * 64) {
            const int lane = g2 & 63;
            const int tk   = g2 >> 6;       // T*16 + kt
            const int kt   = tk & 15, T = tk >> 4;
            const int col  = T * 16 + (lane & 15);
            const int k    = kt * 32 + (lane >> 4) * 8;
            const float* src = W2 + (size_t)col * HDIM + k;
            const int d = col / PDIM;
            half8 v;
            #pragma unroll
            for (int e = 0; e < 8; ++e)
                v[e] = (_Float16)((d > ((k + e) % 63)) ? src[e] : 0.0f);
            *(half8*)(W2g + (size_t)g2 * 8) = v;
        }
    }
}

// ---------------------------------------------------------------------------
// fast transcendentals (validated round 5)
// ---------------------------------------------------------------------------
__device__ __forceinline__ float fexp(float v)  { return __expf(v); }
__device__ __forceinline__ float flog(float v)  { return __logf(v); }
__device__ __forceinline__ float fdiv(float a, float b) { return __fdividef(a, b); }

// ---------------------------------------------------------------------------
// rational-quadratic spline (validated rounds 1-9)
// ---------------------------------------------------------------------------
__device__ __forceinline__ void rqs_eval(const float* prm, float xorig,
                                         float& yo, float& ldo) {
    const float xc = fminf(fmaxf(xorig, -RQ_BOUND), RQ_BOUND);
    const bool inside = (xorig >= -RQ_BOUND) && (xorig <= RQ_BOUND);

    float xk[KBINS + 1], yk[KBINS + 1], dd[KBINS + 1];
    {
        float m = prm[0];
        #pragma unroll
        for (int i = 1; i < KBINS; ++i) m = fmaxf(m, prm[i]);
        float e[KBINS]; float s = 0.0f;
        #pragma unroll
        for (int i = 0; i < KBINS; ++i) { e[i] = fexp(prm[i] - m); s += e[i]; }
        const float inv = fdiv(1.0f, s);
        float c = 0.0f;
        xk[0] = -RQ_BOUND;
        #pragma unroll
        for (int i = 0; i < KBINS; ++i) {
            float w = RQ_MINBIN + (1.0f - RQ_MINBIN * KBINS) * (e[i] * inv);
            c += w;
            xk[i + 1] = -RQ_BOUND + 2.0f * RQ_BOUND * c;
        }
        xk[KBINS] = RQ_BOUND;
    }
    {
        float m = prm[8];
        #pragma unroll
        for (int i = 1; i < KBINS; ++i) m = fmaxf(m, prm[8 + i]);
        float e[KBINS]; float s = 0.0f;
        #pragma unroll
        for (int i = 0; i < KBINS; ++i) { e[i] = fexp(prm[8 + i] - m); s += e[i]; }
        const float inv = fdiv(1.0f, s);
        float c = 0.0f;
        yk[0] = -RQ_BOUND;
        #pragma unroll
        for (int i = 0; i < KBINS; ++i) {
            float h = RQ_MINBIN + (1.0f - RQ_MINBIN * KBINS) * (e[i] * inv);
            c += h;
            yk[i + 1] = -RQ_BOUND + 2.0f * RQ_BOUND * c;
        }
        yk[KBINS] = RQ_BOUND;
    }
    dd[0] = 1.0f;
    #pragma unroll
    for (int i = 0; i < KBINS - 1; ++i) {
        const float v = prm[16 + i];
        const float e = fexp(-fabsf(v));
        dd[i + 1] = RQ_MINDER + flog(1.0f + e) + fmaxf(v, 0.0f);
    }
    dd[KBINS] = 1.0f;

    int idx = 0;
    #pragma unroll
    for (int i = 1; i < KBINS; ++i) idx += (xc >= xk[i]) ? 1 : 0;

    float x_k = xk[0], x_k1 = xk[1];
    float y_k = yk[0], y_k1 = yk[1];
    float d_k = dd[0], d_k1 = dd[1];
    #pragma unroll
    for (int i = 1; i < KBINS; ++i) {
        const bool mm = (idx == i);
        x_k  = mm ? xk[i]     : x_k;
        x_k1 = mm ? xk[i + 1] : x_k1;
        y_k  = mm ? yk[i]     : y_k;
        y_k1 = mm ? yk[i + 1] : y_k1;
        d_k  = mm ? dd[i]     : d_k;
        d_k1 = mm ? dd[i + 1] : d_k1;
    }

    const float w_k = x_k1 - x_k;
    const float h_k = y_k1 - y_k;
    const float rw  = fdiv(1.0f, w_k);
    const float s   = h_k * rw;
    const float th  = (xc - x_k) * rw;
    const float omt = 1.0f - th;
    const float t1m = th * omt;
    const float num = h_k * (s * th * th + d_k * t1m);
    const float den = s + (d_k1 + d_k - 2.0f * s) * t1m;
    const float yin = y_k + fdiv(num, den);
    const float dnum = s * s * (d_k1 * th * th + 2.0f * s * t1m + d_k * omt * omt);
    const float ldin = flog(dnum) - 2.0f * flog(den);

    yo  = inside ? yin : xorig;
    ldo = inside ? ldin : 0.0f;
}

// ---------------------------------------------------------------------------
// fused fp16 MFMA kernel — EXACT round-5 structure (validated best, 207µs);
// single change: W1/W2 loads now hit the fragment-major layout, so each
// B-frag read is one fully-coalesced 1KB wave load (was 16 scattered 64B
// segments per instruction — the suspected ~7.5TB/s W2-delivery serializer).
// ---------------------------------------------------------------------------
__global__ __launch_bounds__(512, 4) void fused_flow(
    const float* __restrict__ x,  const float* __restrict__ b1,
    const float* __restrict__ b2, const _Float16* __restrict__ W1g,
    const _Float16* __restrict__ W2g,
    float* __restrict__ z_out, float* __restrict__ ld_out)
{
    __shared__ __align__(16) ushort_t hm[BM * 512];      // 32 KB fp16, swizzled
    __shared__ __align__(16) float pstage[BM * PSTRIDE]; // 46.5 KB

    const int t    = threadIdx.x;
    const int row0 = blockIdx.x * BM;
    const int wv   = t >> 6;
    const int lane = t & 63;
    const int l15  = lane & 15;
    const int lg   = lane >> 4;

    char* hmB = (char*)hm;

    // ---- phase 1: GEMM1 (x from global, W1g fragment-major) -> hm fp16 ----
    {
        f32x4 acc1[4][2];
        #pragma unroll
        for (int j = 0; j < 4; ++j)
            #pragma unroll
            for (int m = 0; m < 2; ++m) acc1[j][m] = (f32x4){0.f, 0.f, 0.f, 0.f};

        #pragma unroll
        for (int kt = 0; kt < 2; ++kt) {
            half8 a[2];
            #pragma unroll
            for (int m = 0; m < 2; ++m) {
                const float* xr = x + (size_t)(row0 + m * 16 + l15) * DDIM + kt * 32 + lg * 8;
                const float4 xa = *(const float4*)(xr);
                const float4 xb = *(const float4*)(xr + 4);
                a[m][0] = (_Float16)xa.x; a[m][1] = (_Float16)xa.y;
                a[m][2] = (_Float16)xa.z; a[m][3] = (_Float16)xa.w;
                a[m][4] = (_Float16)xb.x; a[m][5] = (_Float16)xb.y;
                a[m][6] = (_Float16)xb.z; a[m][7] = (_Float16)xb.w;
            }
            #pragma unroll
            for (int j = 0; j < 4; ++j) {
                // frag-major: 1KB coalesced per (htile, kt)
                const half8 b = *(const half8*)(W1g + (size_t)(wv * 4 + j) * 1024 + kt * 512 + lane * 8);
                #pragma unroll
                for (int m = 0; m < 2; ++m)
                    acc1[j][m] = __builtin_amdgcn_mfma_f32_16x16x32_f16(a[m], b, acc1[j][m], 0, 0, 0);
            }
        }
        #pragma unroll
        for (int j = 0; j < 4; ++j) {
            const int h = (wv * 4 + j) * 16 + l15;
            const float bias = b1[h];
            #pragma unroll
            for (int m = 0; m < 2; ++m) {
                #pragma unroll
                for (int q = 0; q < 4; ++q) {
                    const int r = m * 16 + lg * 4 + q;
                    const _Float16 hv = (_Float16)fmaxf(acc1[j][m][q] + bias, 0.0f);
                    *(ushort_t*)(hmB + r * 1024 + ((h * 2) ^ ((r & 7) << 4))) =
                        __builtin_bit_cast(ushort_t, hv);
                }
            }
        }
    }
    __syncthreads();

    // ---- phase 2: GEMM2 + spline, 4 chunks ----
    float ldacc = 0.0f;
    const int srow = t >> 4;   // 0..31
    const int sd   = t & 15;   // 0..15
    const int tbase = wv * 3;

    // per-wave fragment-major W2 bases (wave 7's 3rd slot duplicates tile 22)
    const _Float16* w2base[3];
    #pragma unroll
    for (int i = 0; i < 3; ++i) {
        const int tile = (tbase + i < 23) ? (tbase + i) : 22;
        w2base[i] = W2g + (size_t)tile * 8192 + lane * 8;   // tile stride = 16kt*1KB
    }

    for (int c = 0; c < 4; ++c) {
        f32x4 acc[3][2];
        #pragma unroll
        for (int i = 0; i < 3; ++i)
            #pragma unroll
            for (int m = 0; m < 2; ++m) acc[i][m] = (f32x4){0.f, 0.f, 0.f, 0.f};

        const size_t coff = (size_t)c * (23 * 8192);   // chunk = 23 tiles

        #pragma unroll 4
        for (int kt = 0; kt < 16; ++kt) {
            half8 ah[2];
            #pragma unroll
            for (int m = 0; m < 2; ++m) {
                const int r  = m * 16 + l15;
                const int kb = (kt * 32 + lg * 8) * 2;
                ah[m] = *(const half8*)(hmB + r * 1024 + (kb ^ ((r & 7) << 4)));
            }
            half8 bfr[3];
            #pragma unroll
            for (int i = 0; i < 3; ++i)
                bfr[i] = *(const half8*)(w2base[i] + coff + kt * 512);  // 1KB coalesced
            #pragma unroll
            for (int i = 0; i < 3; ++i)
                #pragma unroll
                for (int m = 0; m < 2; ++m)
                    acc[i][m] = __builtin_amdgcn_mfma_f32_16x16x32_f16(ah[m], bfr[i], acc[i][m], 0, 0, 0);
        }

        __syncthreads();   // all waves done reading pstage (spline c-1)

        // stage full chunk (f32)
        #pragma unroll
        for (int i = 0; i < 3; ++i) {
            if (tbase + i < 23) {
                const int lcol = (tbase + i) * 16 + l15;
                #pragma unroll
                for (int m = 0; m < 2; ++m)
                    #pragma unroll
                    for (int q = 0; q < 4; ++q)
                        pstage[(m * 16 + lg * 4 + q) * PSTRIDE + lcol] = acc[i][m][q];
            }
        }
        __syncthreads();

        // spline: one (row, d) per thread — 32 rows x 16 d's = 512
        {
            const int d = c * 16 + sd;
            float prm[PDIM];
            #pragma unroll
            for (int p = 0; p < PDIM; ++p)
                prm[p] = pstage[srow * PSTRIDE + sd * PDIM + p] + b2[d * PDIM + p];
            const float xv = x[(size_t)(row0 + srow) * DDIM + d];
            float yv, lv;
            rqs_eval(prm, xv, yv, lv);
            z_out[(size_t)(row0 + srow) * DDIM + d] = yv;
            ldacc += lv;
        }
        // no barrier here: next kt-loop doesn't touch pstage; stage(c+1) is
        // protected by the barrier after the next kt-loop.
    }

    // ---- logdet: sum the 16 threads of each row ----
    ldacc += __shfl_xor(ldacc, 1, 64);
    ldacc += __shfl_xor(ldacc, 2, 64);
    ldacc += __shfl_xor(ldacc, 4, 64);
    ldacc += __shfl_xor(ldacc, 8, 64);
    if (sd == 0) ld_out[row0 + srow] = ldacc;
}

// ---------------------------------------------------------------------------
extern "C" void kernel_launch(void* const* d_in, const int* in_sizes, int n_in,
                              void* d_out, int out_size, void* d_ws, size_t ws_size,
                              hipStream_t stream) {
    (void)in_sizes; (void)n_in; (void)out_size; (void)ws_size;
    const float* x  = (const float*)d_in[0];
    const float* W1 = (const float*)d_in[1];
    const float* b1 = (const float*)d_in[2];
    const float* W2 = (const float*)d_in[3];
    const float* b2 = (const float*)d_in[4];

    _Float16* W1g = (_Float16*)d_ws;                 // 32768 fp16 (frag-major)
    _Float16* W2g = W1g + HDIM * DDIM;               // 753664 fp16 (frag-major)
    float* z  = (float*)d_out;
    float* ld = z + (size_t)NB * DDIM;

    const int n_groups = 32 * 2 * 64 + NTILES * 16 * 64;   // 98304 fragment-groups
    prep_frag<<<(n_groups + 255) / 256, 256, 0, stream>>>(W1, W2, W1g, W2g);
    fused_flow<<<NB / BM, 512, 0, stream>>>(x, b1, b2, W1g, W2g, z, ld);
}